// Round 6
// baseline (48.634 us; speedup 1.0000x reference)
//
#include <hip/hip_runtime.h>

typedef float f32x4 __attribute__((ext_vector_type(4)));

// B=4096 rows, NPTS=4097 points, M=4096 outputs per row.
constexpr int NPTS = 4097;
constexpr int M    = 4096;
constexpr int TPB  = 256;        // 4 waves
constexpr int NW   = TPB / 64;
constexpr int NJ   = 4;          // element groups (of 4) per row per thread
constexpr int ROWS = 2;          // rows per block
constexpr int NC   = ROWS * NJ;  // scan chains
// element e(j) = j*1024 + tid*4 + i ; rows (2*bid, 2*bid+1)

struct Lds {
    float wt[NW][NC];
    float gram[NW][ROWS * 5];
    float r2s[NW][ROWS];
};

// 4-element trapezoid scan from two aligned f32x4 loads; S = row misalignment
// (compile-time -> no dynamic register indexing, no scratch).
template<int S>
__device__ __forceinline__ void scan4(const f32x4 a, const f32x4 c,
                                      float d0, float d1, float d2, float d3,
                                      float (&xsj)[4], float (&zlj)[4], float& gsj)
{
    const float m[8] = {a.x, a.y, a.z, a.w, c.x, c.y, c.z, c.w};
    const float x0 = m[S+0], x1 = m[S+1], x2 = m[S+2], x3 = m[S+3], x4 = m[S+4];
    const float i0 = d0 * (x0 + x1);
    const float i1 = d1 * (x1 + x2);
    const float i2 = d2 * (x2 + x3);
    const float i3 = d3 * (x3 + x4);
    zlj[0] = i0;
    zlj[1] = i0 + i1;
    zlj[2] = zlj[1] + i2;
    zlj[3] = zlj[2] + i3;
    gsj = zlj[3];
    xsj[0] = x1; xsj[1] = x2; xsj[2] = x3; xsj[3] = x4;
}

template<int S0, bool RHALF>
__device__ __forceinline__ void body(const float* __restrict__ x,
                                     const float* __restrict__ t,
                                     float r, float ny,
                                     float* __restrict__ out,
                                     int b0, int B, Lds& L)
{
    constexpr int S1 = S0 + 1;
    const int tid  = threadIdx.x;
    const int lane = tid & 63;
    const int wid  = tid >> 6;

    // x row base is b*4097 floats; b*4097 ≡ b (mod 4), so (xrow - S) is
    // 16B-aligned with S = b&3. Row b=4095 (S=3) reads end exactly at the
    // last element of x; S<3 rows over-read into the next row (in bounds).
    const float* __restrict__ xal0 = x + (size_t)b0 * NPTS - S0;
    const float* __restrict__ xal1 = x + (size_t)(b0 + 1) * NPTS - S1;

    float xs[ROWS][NJ][4];   // x_sl = x[m+1]
    float zl[ROWS][NJ][4];   // local scan, later z
    float gs[NC];            // group sums

#pragma unroll
    for (int j = 0; j < NJ; ++j) {
        const int e = j * 1024 + tid * 4;
        const f32x4 xa0 = *(const f32x4*)(xal0 + e);
        const f32x4 xc0 = *(const f32x4*)(xal0 + e + 4);
        const f32x4 xa1 = *(const f32x4*)(xal1 + e);
        const f32x4 xc1 = *(const f32x4*)(xal1 + e + 4);
        const f32x4 tq  = *(const f32x4*)(t + e);      // t shared by both rows
        float tn = __shfl_down(tq.x, 1, 64);           // t[e+4] from lane+1
        if (lane == 63) tn = t[e + 4];
        const float d0 = 0.5f * (tq.y - tq.x);
        const float d1 = 0.5f * (tq.z - tq.y);
        const float d2 = 0.5f * (tq.w - tq.z);
        const float d3 = 0.5f * (tn   - tq.w);
        scan4<S0>(xa0, xc0, d0, d1, d2, d3, xs[0][j], zl[0][j], gs[0 * NJ + j]);
        scan4<S1>(xa1, xc1, d0, d1, d2, d3, xs[1][j], zl[1][j], gs[1 * NJ + j]);
    }

    // ---- 8 simultaneous wave inclusive scans of group sums ----
    float sc[NC];
#pragma unroll
    for (int c = 0; c < NC; ++c) sc[c] = gs[c];
#pragma unroll
    for (int d = 1; d < 64; d <<= 1) {
#pragma unroll
        for (int c = 0; c < NC; ++c) {
            float u = __shfl_up(sc[c], d, 64);
            if (lane >= d) sc[c] += u;
        }
    }
    if (lane == 63) {
#pragma unroll
        for (int c = 0; c < NC; ++c) L.wt[wid][c] = sc[c];
    }
    __syncthreads();

    float woff[NC] = {}, Tt[NC] = {};
#pragma unroll
    for (int w = 0; w < NW; ++w) {
#pragma unroll
        for (int c = 0; c < NC; ++c) {
            const float v = L.wt[w][c];
            Tt[c] += v;
            if (w < wid) woff[c] += v;
        }
    }

    float zb[ROWS][NJ];
#pragma unroll
    for (int R = 0; R < ROWS; ++R) {
        float jacc = 0.f;
#pragma unroll
        for (int j = 0; j < NJ; ++j) {
            const int c = R * NJ + j;
            zb[R][j] = ny + jacc + woff[c] + (sc[c] - gs[c]);
            jacc += Tt[c];
        }
    }

    // ---- z, w=z^r, Gram/projection sums in f32 (group-pairwise) ----
    float s[ROWS][5];
#pragma unroll
    for (int R = 0; R < ROWS; ++R)
#pragma unroll
        for (int k = 0; k < 5; ++k) s[R][k] = 0.f;

#pragma unroll
    for (int R = 0; R < ROWS; ++R) {
#pragma unroll
        for (int j = 0; j < NJ; ++j) {
            float pzz = 0, pzw = 0, pww = 0, pxz = 0, pxw = 0;
#pragma unroll
            for (int i = 0; i < 4; ++i) {
                const float z = zb[R][j] + zl[R][j][i];
                zl[R][j][i] = z;
                const float w = RHALF ? sqrtf(z) : powf(z, r);
                const float xv = xs[R][j][i];
                pzz = fmaf(z,  z, pzz);
                pzw = fmaf(z,  w, pzw);
                pww = fmaf(w,  w, pww);
                pxz = fmaf(xv, z, pxz);
                pxw = fmaf(xv, w, pxw);
            }
            s[R][0] += pzz; s[R][1] += pzw; s[R][2] += pww;
            s[R][3] += pxz; s[R][4] += pxw;
        }
    }
#pragma unroll
    for (int d = 32; d > 0; d >>= 1)
#pragma unroll
        for (int R = 0; R < ROWS; ++R)
#pragma unroll
            for (int k = 0; k < 5; ++k)
                s[R][k] += __shfl_down(s[R][k], d, 64);

    if (lane == 0) {
#pragma unroll
        for (int R = 0; R < ROWS; ++R)
#pragma unroll
            for (int k = 0; k < 5; ++k) L.gram[wid][R * 5 + k] = s[R][k];
    }
    __syncthreads();

    // ---- 2x2 normal-equations solve (f64, once per thread, redundant) ----
    float c0[ROWS], c1[ROWS];
#pragma unroll
    for (int R = 0; R < ROWS; ++R) {
        double a0 = 0, a1 = 0, a2 = 0, a3 = 0, a4 = 0;
#pragma unroll
        for (int w = 0; w < NW; ++w) {
            a0 += L.gram[w][R * 5 + 0];
            a1 += L.gram[w][R * 5 + 1];
            a2 += L.gram[w][R * 5 + 2];
            a3 += L.gram[w][R * 5 + 3];
            a4 += L.gram[w][R * 5 + 4];
        }
        const double det = a0 * a2 - a1 * a1;
        const double inv = 1.0 / det;
        const double cc0 = (a3 * a2 - a4 * a1) * inv;
        const double cc1 = (a4 * a0 - a3 * a1) * inv;
        c0[R] = (float)cc0;
        c1[R] = (float)cc1;
        if (tid == R) {
            out[(size_t)(b0 + R) * 2 + 0] = (float)cc0;
            out[(size_t)(b0 + R) * 2 + 1] = (float)cc1;
        }
    }

    // ---- x_hat, res (regular coalesced f32x4 stores), r2 ----
    float r2[ROWS] = {};
#pragma unroll
    for (int R = 0; R < ROWS; ++R) {
        float* __restrict__ xhat = out + (size_t)B * 2 + (size_t)(b0 + R) * M;
        float* __restrict__ res  = xhat + (size_t)B * M;
#pragma unroll
        for (int j = 0; j < NJ; ++j) {
            const int e = j * 1024 + tid * 4;
            f32x4 hv, rv;
#pragma unroll
            for (int i = 0; i < 4; ++i) {
                const float z = zl[R][j][i];
                const float w = RHALF ? sqrtf(z) : powf(z, r);
                const float h  = c0[R] * z + c1[R] * w;
                const float ev = xs[R][j][i] - h;
                hv[i] = h; rv[i] = ev;
                r2[R] = fmaf(ev, ev, r2[R]);
            }
            *(f32x4*)(xhat + e) = hv;
            *(f32x4*)(res  + e) = rv;
        }
    }
#pragma unroll
    for (int d = 32; d > 0; d >>= 1)
#pragma unroll
        for (int R = 0; R < ROWS; ++R) r2[R] += __shfl_down(r2[R], d, 64);
    if (lane == 0) {
        L.r2s[wid][0] = r2[0];
        L.r2s[wid][1] = r2[1];
    }
    __syncthreads();
    if (tid < ROWS) {
        float acc = 0.f;
#pragma unroll
        for (int w = 0; w < NW; ++w) acc += L.r2s[w][tid];
        out[(size_t)B * 2 + 2 * (size_t)B * M + (b0 + tid)] = acc;
    }
}

__global__ __launch_bounds__(TPB)
void vp_kernel(const float* __restrict__ x, const float* __restrict__ t,
               const float* __restrict__ params, float* __restrict__ out, int B)
{
    __shared__ Lds L;
    const float r  = params[0];
    const float ny = params[1];
    const int  b0  = blockIdx.x * 2;
    const bool odd = blockIdx.x & 1;   // b0&3 = 2*(bid&1)

    if (r == 0.5f) {
        if (odd) body<2, true >(x, t, r, ny, out, b0, B, L);
        else     body<0, true >(x, t, r, ny, out, b0, B, L);
    } else {
        if (odd) body<2, false>(x, t, r, ny, out, b0, B, L);
        else     body<0, false>(x, t, r, ny, out, b0, B, L);
    }
}

extern "C" void kernel_launch(void* const* d_in, const int* in_sizes, int n_in,
                              void* d_out, int out_size, void* d_ws, size_t ws_size,
                              hipStream_t stream) {
    const float* x = (const float*)d_in[0];
    const float* t = (const float*)d_in[1];
    const float* p = (const float*)d_in[2];
    float* out     = (float*)d_out;
    const int B    = in_sizes[0] / NPTS;   // 4096

    vp_kernel<<<dim3(B / 2), dim3(TPB), 0, stream>>>(x, t, p, out, B);
}

// Round 7
// 48.510 us; speedup vs baseline: 1.0025x; 1.0025x over previous
//
#include <hip/hip_runtime.h>

typedef float f32x4 __attribute__((ext_vector_type(4)));

// B=4096 rows, NPTS=4097 points, M=4096 outputs per row.
constexpr int NPTS = 4097;
constexpr int M    = 4096;
constexpr int TPB  = 256;        // 4 waves
constexpr int NW   = TPB / 64;
constexpr int NJ   = 4;          // element groups (of 4) per row per thread
constexpr int ROWS = 2;          // rows per block
constexpr int NC   = ROWS * NJ;  // scan chains
// element e(j) = j*1024 + tid*4 + i ; rows (2*bid, 2*bid+1)

struct Lds {
    float wt[NW][NC];
    float gram[NW][ROWS * 5];
    float r2s[NW][ROWS];
};

// 4-element trapezoid scan from two aligned f32x4 loads; S = row misalignment
// (compile-time -> no dynamic register indexing, no scratch).
template<int S>
__device__ __forceinline__ void scan4(const f32x4 a, const f32x4 c,
                                      float d0, float d1, float d2, float d3,
                                      float (&xsj)[4], float (&zlj)[4], float& gsj)
{
    const float m[8] = {a.x, a.y, a.z, a.w, c.x, c.y, c.z, c.w};
    const float x0 = m[S+0], x1 = m[S+1], x2 = m[S+2], x3 = m[S+3], x4 = m[S+4];
    const float i0 = d0 * (x0 + x1);
    const float i1 = d1 * (x1 + x2);
    const float i2 = d2 * (x2 + x3);
    const float i3 = d3 * (x3 + x4);
    zlj[0] = i0;
    zlj[1] = i0 + i1;
    zlj[2] = zlj[1] + i2;
    zlj[3] = zlj[2] + i3;
    gsj = zlj[3];
    xsj[0] = x1; xsj[1] = x2; xsj[2] = x3; xsj[3] = x4;
}

template<int S0, bool RHALF>
__device__ __forceinline__ void body(const float* __restrict__ x,
                                     const float* __restrict__ t,
                                     float r, float ny,
                                     float* __restrict__ out,
                                     int b0, int B, Lds& L)
{
    constexpr int S1 = S0 + 1;
    const int tid  = threadIdx.x;
    const int lane = tid & 63;
    const int wid  = tid >> 6;

    // x row base is b*4097 floats; b*4097 ≡ b (mod 4), so (xrow - S) is
    // 16B-aligned with S = b&3. Row b=4095 (S=3) reads end exactly at the
    // last element of x; S<3 rows over-read into the next row (in bounds).
    const float* __restrict__ xal0 = x + (size_t)b0 * NPTS - S0;
    const float* __restrict__ xal1 = x + (size_t)(b0 + 1) * NPTS - S1;

    float xs[ROWS][NJ][4];   // x_sl = x[m+1]
    float zl[ROWS][NJ][4];   // local scan, later z
    float gs[NC];            // group sums

#pragma unroll
    for (int j = 0; j < NJ; ++j) {
        const int e = j * 1024 + tid * 4;
        const f32x4 xa0 = *(const f32x4*)(xal0 + e);
        const f32x4 xc0 = *(const f32x4*)(xal0 + e + 4);
        const f32x4 xa1 = *(const f32x4*)(xal1 + e);
        const f32x4 xc1 = *(const f32x4*)(xal1 + e + 4);
        const f32x4 tq  = *(const f32x4*)(t + e);      // t shared by both rows
        float tn = __shfl_down(tq.x, 1, 64);           // t[e+4] from lane+1
        if (lane == 63) tn = t[e + 4];
        const float d0 = 0.5f * (tq.y - tq.x);
        const float d1 = 0.5f * (tq.z - tq.y);
        const float d2 = 0.5f * (tq.w - tq.z);
        const float d3 = 0.5f * (tn   - tq.w);
        scan4<S0>(xa0, xc0, d0, d1, d2, d3, xs[0][j], zl[0][j], gs[0 * NJ + j]);
        scan4<S1>(xa1, xc1, d0, d1, d2, d3, xs[1][j], zl[1][j], gs[1 * NJ + j]);
    }

    // ---- 8 simultaneous wave inclusive scans of group sums ----
    float sc[NC];
#pragma unroll
    for (int c = 0; c < NC; ++c) sc[c] = gs[c];
#pragma unroll
    for (int d = 1; d < 64; d <<= 1) {
#pragma unroll
        for (int c = 0; c < NC; ++c) {
            float u = __shfl_up(sc[c], d, 64);
            if (lane >= d) sc[c] += u;
        }
    }
    if (lane == 63) {
#pragma unroll
        for (int c = 0; c < NC; ++c) L.wt[wid][c] = sc[c];
    }
    __syncthreads();

    float woff[NC] = {}, Tt[NC] = {};
#pragma unroll
    for (int w = 0; w < NW; ++w) {
#pragma unroll
        for (int c = 0; c < NC; ++c) {
            const float v = L.wt[w][c];
            Tt[c] += v;
            if (w < wid) woff[c] += v;
        }
    }

    float zb[ROWS][NJ];
#pragma unroll
    for (int R = 0; R < ROWS; ++R) {
        float jacc = 0.f;
#pragma unroll
        for (int j = 0; j < NJ; ++j) {
            const int c = R * NJ + j;
            zb[R][j] = ny + jacc + woff[c] + (sc[c] - gs[c]);
            jacc += Tt[c];
        }
    }

    // ---- z, w=z^r, Gram/projection sums in f32 (group-pairwise) ----
    float s[ROWS][5];
#pragma unroll
    for (int R = 0; R < ROWS; ++R)
#pragma unroll
        for (int k = 0; k < 5; ++k) s[R][k] = 0.f;

#pragma unroll
    for (int R = 0; R < ROWS; ++R) {
#pragma unroll
        for (int j = 0; j < NJ; ++j) {
            float pzz = 0, pzw = 0, pww = 0, pxz = 0, pxw = 0;
#pragma unroll
            for (int i = 0; i < 4; ++i) {
                const float z = zb[R][j] + zl[R][j][i];
                zl[R][j][i] = z;
                const float w = RHALF ? sqrtf(z) : powf(z, r);
                const float xv = xs[R][j][i];
                pzz = fmaf(z,  z, pzz);
                pzw = fmaf(z,  w, pzw);
                pww = fmaf(w,  w, pww);
                pxz = fmaf(xv, z, pxz);
                pxw = fmaf(xv, w, pxw);
            }
            s[R][0] += pzz; s[R][1] += pzw; s[R][2] += pww;
            s[R][3] += pxz; s[R][4] += pxw;
        }
    }
#pragma unroll
    for (int d = 32; d > 0; d >>= 1)
#pragma unroll
        for (int R = 0; R < ROWS; ++R)
#pragma unroll
            for (int k = 0; k < 5; ++k)
                s[R][k] += __shfl_down(s[R][k], d, 64);

    if (lane == 0) {
#pragma unroll
        for (int R = 0; R < ROWS; ++R)
#pragma unroll
            for (int k = 0; k < 5; ++k) L.gram[wid][R * 5 + k] = s[R][k];
    }
    __syncthreads();

    // ---- 2x2 normal-equations solve (f64, once per thread, redundant) ----
    float c0[ROWS], c1[ROWS];
#pragma unroll
    for (int R = 0; R < ROWS; ++R) {
        double a0 = 0, a1 = 0, a2 = 0, a3 = 0, a4 = 0;
#pragma unroll
        for (int w = 0; w < NW; ++w) {
            a0 += L.gram[w][R * 5 + 0];
            a1 += L.gram[w][R * 5 + 1];
            a2 += L.gram[w][R * 5 + 2];
            a3 += L.gram[w][R * 5 + 3];
            a4 += L.gram[w][R * 5 + 4];
        }
        const double det = a0 * a2 - a1 * a1;
        const double inv = 1.0 / det;
        const double cc0 = (a3 * a2 - a4 * a1) * inv;
        const double cc1 = (a4 * a0 - a3 * a1) * inv;
        c0[R] = (float)cc0;
        c1[R] = (float)cc1;
        if (tid == R) {
            out[(size_t)(b0 + R) * 2 + 0] = (float)cc0;
            out[(size_t)(b0 + R) * 2 + 1] = (float)cc1;
        }
    }

    // ---- x_hat, res (regular coalesced f32x4 stores), r2 ----
    float r2[ROWS] = {};
#pragma unroll
    for (int R = 0; R < ROWS; ++R) {
        float* __restrict__ xhat = out + (size_t)B * 2 + (size_t)(b0 + R) * M;
        float* __restrict__ res  = xhat + (size_t)B * M;
#pragma unroll
        for (int j = 0; j < NJ; ++j) {
            const int e = j * 1024 + tid * 4;
            f32x4 hv, rv;
#pragma unroll
            for (int i = 0; i < 4; ++i) {
                const float z = zl[R][j][i];
                const float w = RHALF ? sqrtf(z) : powf(z, r);
                const float h  = c0[R] * z + c1[R] * w;
                const float ev = xs[R][j][i] - h;
                hv[i] = h; rv[i] = ev;
                r2[R] = fmaf(ev, ev, r2[R]);
            }
            *(f32x4*)(xhat + e) = hv;
            *(f32x4*)(res  + e) = rv;
        }
    }
#pragma unroll
    for (int d = 32; d > 0; d >>= 1)
#pragma unroll
        for (int R = 0; R < ROWS; ++R) r2[R] += __shfl_down(r2[R], d, 64);
    if (lane == 0) {
        L.r2s[wid][0] = r2[0];
        L.r2s[wid][1] = r2[1];
    }
    __syncthreads();
    if (tid < ROWS) {
        float acc = 0.f;
#pragma unroll
        for (int w = 0; w < NW; ++w) acc += L.r2s[w][tid];
        out[(size_t)B * 2 + 2 * (size_t)B * M + (b0 + tid)] = acc;
    }
}

__global__ __launch_bounds__(TPB)
void vp_kernel(const float* __restrict__ x, const float* __restrict__ t,
               const float* __restrict__ params, float* __restrict__ out, int B)
{
    __shared__ Lds L;
    const float r  = params[0];
    const float ny = params[1];
    const int  b0  = blockIdx.x * 2;
    const bool odd = blockIdx.x & 1;   // b0&3 = 2*(bid&1)

    if (r == 0.5f) {
        if (odd) body<2, true >(x, t, r, ny, out, b0, B, L);
        else     body<0, true >(x, t, r, ny, out, b0, B, L);
    } else {
        if (odd) body<2, false>(x, t, r, ny, out, b0, B, L);
        else     body<0, false>(x, t, r, ny, out, b0, B, L);
    }
}

extern "C" void kernel_launch(void* const* d_in, const int* in_sizes, int n_in,
                              void* d_out, int out_size, void* d_ws, size_t ws_size,
                              hipStream_t stream) {
    const float* x = (const float*)d_in[0];
    const float* t = (const float*)d_in[1];
    const float* p = (const float*)d_in[2];
    float* out     = (float*)d_out;
    const int B    = in_sizes[0] / NPTS;   // 4096

    vp_kernel<<<dim3(B / 2), dim3(TPB), 0, stream>>>(x, t, p, out, B);
}

// Round 8
// 41.288 us; speedup vs baseline: 1.1779x; 1.1749x over previous
//
#include <hip/hip_runtime.h>

typedef float f32x4 __attribute__((ext_vector_type(4)));

// B=4096 rows, NPTS=4097 points, M=4096 outputs per row.
constexpr int NPTS = 4097;
constexpr int M    = 4096;
constexpr int TPB  = 256;   // 4 waves
constexpr int NW   = TPB / 64;
constexpr int NJ   = 4;     // 4 groups of 4 elements per thread; NJ*TPB*4 == M
// thread owns elements e(j) = j*1024 + tid*4 .. +3 (lane-contiguous)

struct Lds {
    float wt[NW][NJ];     // per-wave scanned group totals
    float gram[NW][5];    // per-wave Gram/projection partials
    float r2s[NW];        // per-wave r2 partials
};

// 4-element trapezoid scan from two aligned f32x4 loads; S = row misalignment
// (compile-time -> pure register selects, no scratch).
template<int S>
__device__ __forceinline__ void scan4(const f32x4 a, const f32x4 c,
                                      float d0, float d1, float d2, float d3,
                                      float (&xsj)[4], float (&zlj)[4], float& gsj)
{
    const float m[8] = {a.x, a.y, a.z, a.w, c.x, c.y, c.z, c.w};
    const float x0 = m[S+0], x1 = m[S+1], x2 = m[S+2], x3 = m[S+3], x4 = m[S+4];
    const float i0 = d0 * (x0 + x1);
    const float i1 = d1 * (x1 + x2);
    const float i2 = d2 * (x2 + x3);
    const float i3 = d3 * (x3 + x4);
    zlj[0] = i0;
    zlj[1] = i0 + i1;
    zlj[2] = zlj[1] + i2;
    zlj[3] = zlj[2] + i3;
    gsj = zlj[3];
    xsj[0] = x1; xsj[1] = x2; xsj[2] = x3; xsj[3] = x4;
}

template<int S, bool RHALF>
__device__ __forceinline__ void body(const float* __restrict__ x,
                                     const float* __restrict__ t,
                                     float r, float ny,
                                     float* __restrict__ out,
                                     int b, int B, Lds& L)
{
    const int tid  = threadIdx.x;
    const int lane = tid & 63;
    const int wid  = tid >> 6;

    // x row base = b*4097 floats; b*4097 ≡ b (mod 4) -> (xrow - S), S=b&3, is
    // 16B-aligned. Row b=4095 (S=3) reads end exactly at x's last element;
    // S<3 rows over-read <=3 floats into the next row (in bounds).
    const float* __restrict__ xal = x + (size_t)b * NPTS - S;

    float xs[NJ][4];   // x_sl = x[m+1]
    float zl[NJ][4];   // local scan, later z
    float gs[NJ];      // group sums

#pragma unroll
    for (int j = 0; j < NJ; ++j) {
        const int e = j * 1024 + tid * 4;
        const f32x4 a4 = *(const f32x4*)(xal + e);
        const f32x4 c4 = *(const f32x4*)(xal + e + 4);
        const f32x4 tq = *(const f32x4*)(t + e);       // aligned, L2-hot
        float tn = __shfl_down(tq.x, 1, 64);           // t[e+4] from lane+1
        if (lane == 63) tn = t[e + 4];
        const float d0 = 0.5f * (tq.y - tq.x);
        const float d1 = 0.5f * (tq.z - tq.y);
        const float d2 = 0.5f * (tq.w - tq.z);
        const float d3 = 0.5f * (tn   - tq.w);
        scan4<S>(a4, c4, d0, d1, d2, d3, xs[j], zl[j], gs[j]);
    }

    // ---- 4 simultaneous wave inclusive scans of group sums ----
    float sc[NJ];
#pragma unroll
    for (int c = 0; c < NJ; ++c) sc[c] = gs[c];
#pragma unroll
    for (int d = 1; d < 64; d <<= 1) {
#pragma unroll
        for (int c = 0; c < NJ; ++c) {
            float u = __shfl_up(sc[c], d, 64);
            if (lane >= d) sc[c] += u;
        }
    }
    if (lane == 63) {
#pragma unroll
        for (int c = 0; c < NJ; ++c) L.wt[wid][c] = sc[c];
    }
    __syncthreads();

    float woff[NJ] = {}, Tt[NJ] = {};
#pragma unroll
    for (int w = 0; w < NW; ++w) {
#pragma unroll
        for (int c = 0; c < NJ; ++c) {
            const float v = L.wt[w][c];
            Tt[c] += v;
            if (w < wid) woff[c] += v;
        }
    }
    // exclusive prefix per group; memory order = j-major, tid-minor
    float zb[NJ];
    {
        float jacc = 0.f;
#pragma unroll
        for (int j = 0; j < NJ; ++j) {
            zb[j] = ny + jacc + woff[j] + (sc[j] - gs[j]);
            jacc += Tt[j];
        }
    }

    // ---- z, w=z^r, Gram/projection sums in f32 (group-pairwise) ----
    float s0 = 0, s1 = 0, s2 = 0, s3 = 0, s4 = 0;
#pragma unroll
    for (int j = 0; j < NJ; ++j) {
        float pzz = 0, pzw = 0, pww = 0, pxz = 0, pxw = 0;
#pragma unroll
        for (int i = 0; i < 4; ++i) {
            const float z = zb[j] + zl[j][i];
            zl[j][i] = z;
            const float w = RHALF ? sqrtf(z) : powf(z, r);
            const float xv = xs[j][i];
            pzz = fmaf(z,  z, pzz);
            pzw = fmaf(z,  w, pzw);
            pww = fmaf(w,  w, pww);
            pxz = fmaf(xv, z, pxz);
            pxw = fmaf(xv, w, pxw);
        }
        s0 += pzz; s1 += pzw; s2 += pww; s3 += pxz; s4 += pxw;
    }
#pragma unroll
    for (int d = 32; d > 0; d >>= 1) {
        s0 += __shfl_down(s0, d, 64);
        s1 += __shfl_down(s1, d, 64);
        s2 += __shfl_down(s2, d, 64);
        s3 += __shfl_down(s3, d, 64);
        s4 += __shfl_down(s4, d, 64);
    }
    if (lane == 0) {
        L.gram[wid][0] = s0; L.gram[wid][1] = s1; L.gram[wid][2] = s2;
        L.gram[wid][3] = s3; L.gram[wid][4] = s4;
    }
    __syncthreads();

    // ---- 2x2 normal-equations solve (f64, redundant per-thread; LDS
    //      broadcast reads, no extra barrier) ----
    double a0 = 0, a1 = 0, a2 = 0, a3 = 0, a4 = 0;
#pragma unroll
    for (int w = 0; w < NW; ++w) {
        a0 += L.gram[w][0]; a1 += L.gram[w][1]; a2 += L.gram[w][2];
        a3 += L.gram[w][3]; a4 += L.gram[w][4];
    }
    const double det = a0 * a2 - a1 * a1;
    const double inv = 1.0 / det;
    const float c0 = (float)((a3 * a2 - a4 * a1) * inv);
    const float c1 = (float)((a4 * a0 - a3 * a1) * inv);
    if (tid == 0) {
        out[(size_t)b * 2 + 0] = c0;
        out[(size_t)b * 2 + 1] = c1;
    }

    // ---- x_hat, res (regular coalesced f32x4 stores), r2 ----
    float* __restrict__ xhat = out + (size_t)B * 2 + (size_t)b * M;
    float* __restrict__ res  = xhat + (size_t)B * M;

    float r2 = 0.f;
#pragma unroll
    for (int j = 0; j < NJ; ++j) {
        const int e = j * 1024 + tid * 4;
        f32x4 hv, rv;
#pragma unroll
        for (int i = 0; i < 4; ++i) {
            const float z = zl[j][i];
            const float w = RHALF ? sqrtf(z) : powf(z, r);
            const float h  = c0 * z + c1 * w;
            const float ev = xs[j][i] - h;
            hv[i] = h; rv[i] = ev;
            r2 = fmaf(ev, ev, r2);
        }
        *(f32x4*)(xhat + e) = hv;
        *(f32x4*)(res  + e) = rv;
    }
#pragma unroll
    for (int d = 32; d > 0; d >>= 1) r2 += __shfl_down(r2, d, 64);
    if (lane == 0) L.r2s[wid] = r2;
    __syncthreads();
    if (tid == 0) {
        float acc = 0.f;
#pragma unroll
        for (int w = 0; w < NW; ++w) acc += L.r2s[w];
        out[(size_t)B * 2 + 2 * (size_t)B * M + b] = acc;
    }
}

__global__ __launch_bounds__(TPB)
void vp_kernel(const float* __restrict__ x, const float* __restrict__ t,
               const float* __restrict__ params, float* __restrict__ out, int B)
{
    __shared__ Lds L;
    const float r  = params[0];
    const float ny = params[1];
    const int  b   = blockIdx.x;

    if (r == 0.5f) {
        switch (b & 3) {
        case 0:  body<0, true>(x, t, r, ny, out, b, B, L); break;
        case 1:  body<1, true>(x, t, r, ny, out, b, B, L); break;
        case 2:  body<2, true>(x, t, r, ny, out, b, B, L); break;
        default: body<3, true>(x, t, r, ny, out, b, B, L); break;
        }
    } else {
        switch (b & 3) {
        case 0:  body<0, false>(x, t, r, ny, out, b, B, L); break;
        case 1:  body<1, false>(x, t, r, ny, out, b, B, L); break;
        case 2:  body<2, false>(x, t, r, ny, out, b, B, L); break;
        default: body<3, false>(x, t, r, ny, out, b, B, L); break;
        }
    }
}

extern "C" void kernel_launch(void* const* d_in, const int* in_sizes, int n_in,
                              void* d_out, int out_size, void* d_ws, size_t ws_size,
                              hipStream_t stream) {
    const float* x = (const float*)d_in[0];
    const float* t = (const float*)d_in[1];
    const float* p = (const float*)d_in[2];
    float* out     = (float*)d_out;
    const int B    = in_sizes[0] / NPTS;   // 4096

    vp_kernel<<<dim3(B), dim3(TPB), 0, stream>>>(x, t, p, out, B);
}